// Round 16
// baseline (388.148 us; speedup 1.0000x reference)
//
#include <hip/hip_runtime.h>
#include <stdint.h>

#define BB 4
#define LL 16384
#define CC 512
#define MM (BB * LL)  // 65536

typedef unsigned short u16;
typedef __bf16 bf16x8 __attribute__((ext_vector_type(8)));
typedef float f32x4 __attribute__((ext_vector_type(4)));
typedef u16 u16x8 __attribute__((ext_vector_type(8)));
typedef u16 u16x4 __attribute__((ext_vector_type(4)));
typedef u16 u16x2 __attribute__((ext_vector_type(2)));

__device__ __forceinline__ u16 f2bf(float f) {
  return __builtin_bit_cast(u16, (__bf16)f);
}

__device__ __forceinline__ void gl_lds16(const void* g, void* l) {
  __builtin_amdgcn_global_load_lds((const __attribute__((address_space(1))) void*)g,
                                   (__attribute__((address_space(3))) void*)l,
                                   16, 0, 0);
}

// ---------------- fused prep: fp32->bf16 cvt (q,kv) + weight transpose-cvt ----------
// (round 14: dense per-instruction coalescing + 16 loads in flight; ~HBM-bound)
__global__ __launch_bounds__(256) void prep_kernel(
    const float* __restrict__ q, const float* __restrict__ kv,
    const float* __restrict__ Wq, const float* __restrict__ Wkv,
    const float* __restrict__ Wfc, u16* __restrict__ qo, u16* __restrict__ kvo,
    u16* __restrict__ Wq_t, u16* __restrict__ Wkv_t, u16* __restrict__ Wfc_t) {
  __shared__ float tile[64][65];
  const int bid = blockIdx.x, tid = threadIdx.x;

  if (bid < 4096) {
    const int half = bid >> 11;
    const float* src = half ? kv : q;
    u16* dst = half ? kvo : qo;
    const int lb = bid & 2047;
    const int c0 = lb * 4096;
    f32x4 v[16];
#pragma unroll
    for (int k = 0; k < 16; ++k)
      v[k] = __builtin_nontemporal_load(reinterpret_cast<const f32x4*>(src) + c0 + k * 256 + tid);
#pragma unroll
    for (int k = 0; k < 8; ++k) {
      u16x8 o;
#pragma unroll
      for (int e = 0; e < 4; ++e) o[e] = f2bf(v[2 * k][e]);
#pragma unroll
      for (int e = 0; e < 4; ++e) o[4 + e] = f2bf(v[2 * k + 1][e]);
      *reinterpret_cast<u16x4*>(dst + (size_t)(c0 + 2 * k * 256 + tid) * 4) =
          (u16x4){o[0], o[1], o[2], o[3]};
      *reinterpret_cast<u16x4*>(dst + (size_t)(c0 + (2 * k + 1) * 256 + tid) * 4) =
          (u16x4){o[4], o[5], o[6], o[7]};
    }
    return;
  }

  // weight transpose: W[K][N] -> Wt[N][K] bf16, 64x64 tiles
  const int wb = bid - 4096;
  const float* W; u16* Wt; int N, ti;
  if (wb < 64)       { W = Wq;  Wt = Wq_t;  N = 512;  ti = wb; }
  else if (wb < 192) { W = Wkv; Wt = Wkv_t; N = 1024; ti = wb - 64; }
  else               { W = Wfc; Wt = Wfc_t; N = 512;  ti = wb - 192; }
  const int ntn = N >> 6;
  const int kt = ti / ntn, nt = ti % ntn;
  const int k0 = kt << 6, n0 = nt << 6;
  {
    const int r = tid >> 4, c4 = tid & 15;
#pragma unroll
    for (int e = 0; e < 4; ++e) {
      int row = r + e * 16;
      f32x4 v = *reinterpret_cast<const f32x4*>(&W[(size_t)(k0 + row) * N + n0 + c4 * 4]);
      tile[row][c4 * 4 + 0] = v[0]; tile[row][c4 * 4 + 1] = v[1];
      tile[row][c4 * 4 + 2] = v[2]; tile[row][c4 * 4 + 3] = v[3];
    }
  }
  __syncthreads();
  {
    const int n = tid >> 2, qd = tid & 3;
#pragma unroll
    for (int e = 0; e < 2; ++e) {
      int c = qd * 2 + e;
      u16x8 o;
#pragma unroll
      for (int j = 0; j < 8; ++j) o[j] = f2bf(tile[c * 8 + j][n]);
      *reinterpret_cast<u16x8*>(&Wt[(size_t)(n0 + n) * 512 + k0 + c * 8]) = o;
    }
  }
}

// -------- 256x128 NT GEMM @ 2 blocks/CU: C[M][N] = A[M][512] * Bt[N][512]^T --------
// 8 waves (4M x 2N, 64x64/wave). LDS exactly 80KB: A double-buffer (2x32KB) +
// B single-buffer (16KB) -> 2 blocks/CU (the co-residency fix: another block
// fills DS/MFMA/drain gaps). 4 phases/tile, counted lgkmcnt fragment pipeline.
// Ledger: stageA(u+1)->idle A buf @p0 (readers closed at tile u-1 end barrier);
// all B-frag reads issued+drained before p0-end barrier -> stageB(u+1) @p1 is
// race-free; tile-end vmcnt(0)+barrier publishes both (A: 4 phases cover;
// B: weights are L2-resident ~200cy, 3 phases cover).
template <bool OUT_F32>
__global__ __launch_bounds__(512, 4) void gemm256(const u16* __restrict__ A,
                                                  const u16* __restrict__ Bt,
                                                  void* __restrict__ Cp,
                                                  int N, int nbnl) {
  constexpr int K = 512;
  constexpr int NT = 8;
  __shared__ __align__(16) u16 Al[2][16384];
  __shared__ __align__(16) u16 Bl[8192];
  const int nwg = gridDim.x;
  const int bid0 = blockIdx.x;
  const int cpx = nwg >> 3;
  const int bid = (bid0 & 7) * cpx + (bid0 >> 3);
  const int bm = bid >> nbnl, bn = bid & ((1 << nbnl) - 1);
  const size_t row0 = (size_t)bm << 8, col0 = (size_t)bn << 7;
  const int tid = threadIdx.x, lane = tid & 63;
  const int wv = tid >> 6, wm = wv >> 1, wn = wv & 1;
  const int ro = lane & 15, g4 = lane >> 4;

  // staging: chunk cc = (row r = cc>>3, colgroup g = cc&7); LDS dest LINEAR,
  // global source colgroup pre-swizzled g^(r&7).
  auto stageA = [&](int kt, u16* L) {
#pragma unroll
    for (int c = 0; c < 4; ++c) {
      int cc = tid + c * 512;
      int r = cc >> 3, g = (cc & 7) ^ (r & 7);
      gl_lds16(A + (row0 + r) * (size_t)K + kt * 64 + g * 8, L + cc * 8);
    }
  };
  auto stageB = [&](int kt) {
#pragma unroll
    for (int c = 0; c < 2; ++c) {
      int cc = tid + c * 512;
      int r = cc >> 3, g = (cc & 7) ^ (r & 7);
      gl_lds16(Bt + (col0 + r) * (size_t)K + kt * 64 + g * 8, Bl + cc * 8);
    }
  };

  // ds_read offsets (u16 elems), swizzled: phys colgroup = logical ^ (row&7)
  const int aB = (wm * 64 + ro) * 64;
  const int bB = (wn * 64 + ro) * 64;
  const int sw0 = (g4 ^ (ro & 7)) * 8;
  const int sw1 = ((g4 + 4) ^ (ro & 7)) * 8;

  auto ldf = [&](const u16* p) { return *reinterpret_cast<const bf16x8*>(p); };

  f32x4 acc[4][4] = {};

  // prologue: stage tile 0, full drain
  stageA(0, Al[0]); stageB(0);
  asm volatile("s_waitcnt vmcnt(0)" ::: "memory");
  __builtin_amdgcn_s_barrier();

  for (int u = 0; u < NT; ++u) {
    u16* LA = Al[u & 1];
    u16* LAn = Al[(u + 1) & 1];
    const bool st = (u + 1) < NT;
    bf16x8 bfr[4][2], afa[2], afb[2];

    // ---- p0: all B frags + A(m0); stage A(u+1); issue A(m1); MFMA m0 ----
#pragma unroll
    for (int n = 0; n < 4; ++n) {
      bfr[n][0] = ldf(Bl + bB + n * 1024 + sw0);
      bfr[n][1] = ldf(Bl + bB + n * 1024 + sw1);
    }
    afa[0] = ldf(LA + aB + sw0); afa[1] = ldf(LA + aB + sw1);
    if (st) stageA(u + 1, LAn);
    asm volatile("s_waitcnt lgkmcnt(0)" ::: "memory");
    __builtin_amdgcn_sched_barrier(0);
    afb[0] = ldf(LA + aB + 1024 + sw0); afb[1] = ldf(LA + aB + 1024 + sw1);
    __builtin_amdgcn_sched_barrier(0);
    __builtin_amdgcn_s_setprio(1);
#pragma unroll
    for (int n = 0; n < 4; ++n) {
      acc[0][n] = __builtin_amdgcn_mfma_f32_16x16x32_bf16(afa[0], bfr[n][0], acc[0][n], 0, 0, 0);
      acc[0][n] = __builtin_amdgcn_mfma_f32_16x16x32_bf16(afa[1], bfr[n][1], acc[0][n], 0, 0, 0);
    }
    __builtin_amdgcn_s_setprio(0);
    __builtin_amdgcn_s_barrier();  // all waves' B reads of tile u complete

    // ---- p1: stage B(u+1) into (closed) B buffer; issue A(m2); MFMA m1 ----
    if (st) stageB(u + 1);
    afa[0] = ldf(LA + aB + 2048 + sw0); afa[1] = ldf(LA + aB + 2048 + sw1);
    asm volatile("s_waitcnt lgkmcnt(2)" ::: "memory");  // afb (m1) ready
    __builtin_amdgcn_sched_barrier(0);
    __builtin_amdgcn_s_setprio(1);
#pragma unroll
    for (int n = 0; n < 4; ++n) {
      acc[1][n] = __builtin_amdgcn_mfma_f32_16x16x32_bf16(afb[0], bfr[n][0], acc[1][n], 0, 0, 0);
      acc[1][n] = __builtin_amdgcn_mfma_f32_16x16x32_bf16(afb[1], bfr[n][1], acc[1][n], 0, 0, 0);
    }
    __builtin_amdgcn_s_setprio(0);

    // ---- p2: issue A(m3); MFMA m2 ----
    afb[0] = ldf(LA + aB + 3072 + sw0); afb[1] = ldf(LA + aB + 3072 + sw1);
    asm volatile("s_waitcnt lgkmcnt(2)" ::: "memory");  // afa (m2) ready
    __builtin_amdgcn_sched_barrier(0);
    __builtin_amdgcn_s_setprio(1);
#pragma unroll
    for (int n = 0; n < 4; ++n) {
      acc[2][n] = __builtin_amdgcn_mfma_f32_16x16x32_bf16(afa[0], bfr[n][0], acc[2][n], 0, 0, 0);
      acc[2][n] = __builtin_amdgcn_mfma_f32_16x16x32_bf16(afa[1], bfr[n][1], acc[2][n], 0, 0, 0);
    }
    __builtin_amdgcn_s_setprio(0);

    // ---- p3: MFMA m3; tile-end drain + publish ----
    asm volatile("s_waitcnt lgkmcnt(0)" ::: "memory");  // afb (m3) ready
    __builtin_amdgcn_sched_barrier(0);
    __builtin_amdgcn_s_setprio(1);
#pragma unroll
    for (int n = 0; n < 4; ++n) {
      acc[3][n] = __builtin_amdgcn_mfma_f32_16x16x32_bf16(afb[0], bfr[n][0], acc[3][n], 0, 0, 0);
      acc[3][n] = __builtin_amdgcn_mfma_f32_16x16x32_bf16(afb[1], bfr[n][1], acc[3][n], 0, 0, 0);
    }
    __builtin_amdgcn_s_setprio(0);
    asm volatile("s_waitcnt vmcnt(0)" ::: "memory");  // staged A(u+1)+B(u+1) landed
    __builtin_amdgcn_s_barrier();
  }

  // epilogue: C write
#pragma unroll
  for (int m = 0; m < 4; ++m)
#pragma unroll
    for (int n = 0; n < 4; ++n)
#pragma unroll
      for (int j = 0; j < 4; ++j) {
        size_t r = row0 + wm * 64 + m * 16 + g4 * 4 + j;
        size_t c = col0 + wn * 64 + n * 16 + ro;
        if (OUT_F32)
          reinterpret_cast<float*>(Cp)[r * N + c] = acc[m][n][j];
        else
          reinterpret_cast<u16*>(Cp)[r * N + c] = f2bf(acc[m][n][j]);
      }
}

// ---------------- window attention (round-6 structure + VALU diet) ----------------
__global__ __launch_bounds__(512, 4) void attn_kernel(const u16* __restrict__ qp,
                                                      const u16* __restrict__ kvp,
                                                      u16* __restrict__ o) {
  __shared__ __align__(16) u16 Kl[256 * 64];
  __shared__ __align__(16) u16 Vt[64 * 256];
  __shared__ __align__(16) u16 Pl[8 * 1024];
  const int bid = blockIdx.x;
  const int h = bid & 7, w = (bid >> 3) & 63, b = bid >> 9;
  const int w1 = w >> 3, w2 = w & 7;
  const int tid = threadIdx.x, lane = tid & 63, wv = tid >> 6;

  auto lrow = [&](int t) { return (w1 * 16 + (t >> 4)) * 128 + w2 * 16 + (t & 15); };

#pragma unroll
  for (int p = 0; p < 4; ++p) {
    int ci = tid + p * 512;
    int r = ci >> 3, g = (ci & 7) ^ (r & 7);
    gl_lds16(kvp + ((size_t)(b * LL + lrow(r))) * 1024 + h * 64 + g * 8, Kl + ci * 8);
  }
  // stage V transposed, swizzled; pairwise b32 writes (2 tokens x 16 d / thread)
  {
    const int pr = tid >> 2;       // token pair 0..127
    const int dg = tid & 3;        // d-group, d0 = dg*16
    const int t0 = 2 * pr;
    const size_t b0 = ((size_t)(b * LL + lrow(t0))) * 1024 + 512 + h * 64 + dg * 16;
    const size_t b1 = ((size_t)(b * LL + lrow(t0 + 1))) * 1024 + 512 + h * 64 + dg * 16;
    u16x8 v00 = *reinterpret_cast<const u16x8*>(kvp + b0);
    u16x8 v01 = *reinterpret_cast<const u16x8*>(kvp + b0 + 8);
    u16x8 v10 = *reinterpret_cast<const u16x8*>(kvp + b1);
    u16x8 v11 = *reinterpret_cast<const u16x8*>(kvp + b1 + 8);
#pragma unroll
    for (int e = 0; e < 8; ++e) {
      int d = dg * 16 + e;
      *reinterpret_cast<u16x2*>(
          &Vt[d * 256 + (((t0 >> 3) ^ (d & 7)) * 8) + (t0 & 7)]) = (u16x2){v00[e], v10[e]};
    }
#pragma unroll
    for (int e = 0; e < 8; ++e) {
      int d = dg * 16 + 8 + e;
      *reinterpret_cast<u16x2*>(
          &Vt[d * 256 + (((t0 >> 3) ^ (d & 7)) * 8) + (t0 & 7)]) = (u16x2){v01[e], v11[e]};
    }
  }
  __syncthreads();

  const int ro = lane & 15;
  const int g4 = lane >> 4;
  const float kk = 0.125f * 1.44269504f;  // scale * log2(e)
  const int swA = (g4 ^ (ro & 7)) * 8;
  const int swB = ((g4 + 4) ^ (ro & 7)) * 8;
  u16* PW = Pl + wv * 1024;

  auto ldf = [&](const u16* p) { return *reinterpret_cast<const bf16x8*>(p); };

#pragma unroll
  for (int rt = 0; rt < 2; ++rt) {
    const int tq = 32 * wv + 16 * rt + ro;
    const size_t qbase = ((size_t)(b * LL + lrow(tq))) * 512 + h * 64 + g4 * 8;
    const bf16x8 qf0 = *reinterpret_cast<const bf16x8*>(qp + qbase);
    const bf16x8 qf1 = *reinterpret_cast<const bf16x8*>(qp + qbase + 32);

    f32x4 sa[16] = {};
    __builtin_amdgcn_s_setprio(1);
#pragma unroll
    for (int ct = 0; ct < 16; ++ct) {
      bf16x8 kf0 = ldf(Kl + (16 * ct + ro) * 64 + swA);
      bf16x8 kf1 = ldf(Kl + (16 * ct + ro) * 64 + swB);
      sa[ct] = __builtin_amdgcn_mfma_f32_16x16x32_bf16(qf0, kf0, sa[ct], 0, 0, 0);
      sa[ct] = __builtin_amdgcn_mfma_f32_16x16x32_bf16(qf1, kf1, sa[ct], 0, 0, 0);
    }
    __builtin_amdgcn_s_setprio(0);

    // softmax per q-row: unnormalized P (defer 1/s to O-write), exp2 w/ folded scale
    float inv4[4];
#pragma unroll
    for (int j = 0; j < 4; ++j) {
      float t8[8];
#pragma unroll
      for (int i = 0; i < 8; ++i) t8[i] = fmaxf(sa[i][j], sa[i + 8][j]);
      float t4a = fmaxf(t8[0], t8[1]), t4b = fmaxf(t8[2], t8[3]);
      float t4c = fmaxf(t8[4], t8[5]), t4d = fmaxf(t8[6], t8[7]);
      float m = fmaxf(fmaxf(t4a, t4b), fmaxf(t4c, t4d));
      m = fmaxf(m, __shfl_xor(m, 1));
      m = fmaxf(m, __shfl_xor(m, 2));
      m = fmaxf(m, __shfl_xor(m, 4));
      m = fmaxf(m, __shfl_xor(m, 8));
      const float mk = m * kk;
      float s = 0.f;
#pragma unroll
      for (int ct = 0; ct < 16; ++ct) {
        float p = exp2f(sa[ct][j] * kk - mk);
        sa[ct][j] = p;
        s += p;
      }
      s += __shfl_xor(s, 1);
      s += __shfl_xor(s, 2);
      s += __shfl_xor(s, 4);
      s += __shfl_xor(s, 8);
      inv4[j] = 1.f / s;
    }

    f32x4 oacc[4] = {};
#pragma unroll
    for (int kh = 0; kh < 4; ++kh) {
#pragma unroll
      for (int c = 0; c < 4; ++c)
#pragma unroll
        for (int j = 0; j < 4; ++j) {
          int rq = g4 * 4 + j;
          PW[rq * 64 + (((2 * c + (ro >> 3)) ^ (rq & 7)) * 8) + (ro & 7)] =
              f2bf(sa[kh * 4 + c][j]);
        }
      __builtin_amdgcn_s_setprio(1);
#pragma unroll
      for (int ks = 0; ks < 2; ++ks) {
        bf16x8 pf = ldf(PW + ro * 64 + (((ks * 4 + g4) ^ (ro & 7)) * 8));
        const int kkg = kh * 2 + ks;
#pragma unroll
        for (int cd = 0; cd < 4; ++cd) {
          bf16x8 vf = ldf(Vt + (16 * cd + ro) * 256 + (((kkg * 4 + g4) ^ (ro & 7)) * 8));
          oacc[cd] = __builtin_amdgcn_mfma_f32_16x16x32_bf16(pf, vf, oacc[cd], 0, 0, 0);
        }
      }
      __builtin_amdgcn_s_setprio(0);
    }

#pragma unroll
    for (int cd = 0; cd < 4; ++cd)
#pragma unroll
      for (int j = 0; j < 4; ++j) {
        int t = 32 * wv + 16 * rt + g4 * 4 + j;
        int d = 16 * cd + ro;
        o[((size_t)(b * LL + lrow(t))) * 512 + h * 64 + d] = f2bf(oacc[cd][j] * inv4[j]);
      }
  }
}

// ---------------- launch ----------------
extern "C" void kernel_launch(void* const* d_in, const int* in_sizes, int n_in,
                              void* d_out, int out_size, void* d_ws, size_t ws_size,
                              hipStream_t stream) {
  const float* q = (const float*)d_in[0];
  const float* kv = (const float*)d_in[1];
  const float* Wq = (const float*)d_in[2];
  const float* Wkv = (const float*)d_in[3];
  const float* Wfc = (const float*)d_in[4];
  float* out = (float*)d_out;
  char* ws = (char*)d_ws;

  u16* q_bf  = (u16*)(ws + 0);            // 67108864  (also reused as o_buf)
  u16* kv_bf = (u16*)(ws + 67108864);     // 67108864
  u16* qp    = (u16*)(ws + 134217728);    // 67108864
  u16* kvp   = (u16*)(ws + 201326592);    // 134217728
  u16* Wq_t  = (u16*)(ws + 335544320);    // 524288
  u16* Wkv_t = (u16*)(ws + 336068608);    // 1048576
  u16* Wfc_t = (u16*)(ws + 337117184);    // 524288
  u16* o_buf = q_bf;

  prep_kernel<<<4352, 256, 0, stream>>>(q, kv, Wq, Wkv, Wfc, q_bf, kv_bf, Wq_t, Wkv_t, Wfc_t);

  // 256x128 tiles: grid = (M/256) * (N/128)
  gemm256<false><<<(MM / 256) * (CC / 128), 512, 0, stream>>>(q_bf, Wq_t, qp, CC, 2);
  gemm256<false><<<(MM / 256) * (2 * CC / 128), 512, 0, stream>>>(kv_bf, Wkv_t, kvp, 2 * CC, 3);

  attn_kernel<<<BB * 64 * 8, 512, 0, stream>>>(qp, kvp, o_buf);

  gemm256<true><<<(MM / 256) * (CC / 128), 512, 0, stream>>>(o_buf, Wfc_t, out, CC, 2);
}

// Round 17
// 345.533 us; speedup vs baseline: 1.1233x; 1.1233x over previous
//
#include <hip/hip_runtime.h>
#include <stdint.h>

#define BB 4
#define LL 16384
#define CC 512
#define MM (BB * LL)  // 65536

typedef unsigned short u16;
typedef __bf16 bf16x8 __attribute__((ext_vector_type(8)));
typedef float f32x4 __attribute__((ext_vector_type(4)));
typedef u16 u16x8 __attribute__((ext_vector_type(8)));
typedef u16 u16x4 __attribute__((ext_vector_type(4)));
typedef u16 u16x2 __attribute__((ext_vector_type(2)));

__device__ __forceinline__ u16 f2bf(float f) {
  return __builtin_bit_cast(u16, (__bf16)f);
}

__device__ __forceinline__ void gl_lds16(const void* g, void* l) {
  __builtin_amdgcn_global_load_lds((const __attribute__((address_space(1))) void*)g,
                                   (__attribute__((address_space(3))) void*)l,
                                   16, 0, 0);
}

// ---------------- fused prep: fp32->bf16 cvt (q,kv) + weight transpose-cvt ----------
// (round 14: dense per-instruction coalescing + 16 loads in flight)
__global__ __launch_bounds__(256) void prep_kernel(
    const float* __restrict__ q, const float* __restrict__ kv,
    const float* __restrict__ Wq, const float* __restrict__ Wkv,
    const float* __restrict__ Wfc, u16* __restrict__ qo, u16* __restrict__ kvo,
    u16* __restrict__ Wq_t, u16* __restrict__ Wkv_t, u16* __restrict__ Wfc_t) {
  __shared__ float tile[64][65];
  const int bid = blockIdx.x, tid = threadIdx.x;

  if (bid < 4096) {
    const int half = bid >> 11;
    const float* src = half ? kv : q;
    u16* dst = half ? kvo : qo;
    const int lb = bid & 2047;
    const int c0 = lb * 4096;
    f32x4 v[16];
#pragma unroll
    for (int k = 0; k < 16; ++k)
      v[k] = __builtin_nontemporal_load(reinterpret_cast<const f32x4*>(src) + c0 + k * 256 + tid);
#pragma unroll
    for (int k = 0; k < 8; ++k) {
      u16x8 o;
#pragma unroll
      for (int e = 0; e < 4; ++e) o[e] = f2bf(v[2 * k][e]);
#pragma unroll
      for (int e = 0; e < 4; ++e) o[4 + e] = f2bf(v[2 * k + 1][e]);
      *reinterpret_cast<u16x4*>(dst + (size_t)(c0 + 2 * k * 256 + tid) * 4) =
          (u16x4){o[0], o[1], o[2], o[3]};
      *reinterpret_cast<u16x4*>(dst + (size_t)(c0 + (2 * k + 1) * 256 + tid) * 4) =
          (u16x4){o[4], o[5], o[6], o[7]};
    }
    return;
  }

  // weight transpose: W[K][N] -> Wt[N][K] bf16, 64x64 tiles
  const int wb = bid - 4096;
  const float* W; u16* Wt; int N, ti;
  if (wb < 64)       { W = Wq;  Wt = Wq_t;  N = 512;  ti = wb; }
  else if (wb < 192) { W = Wkv; Wt = Wkv_t; N = 1024; ti = wb - 64; }
  else               { W = Wfc; Wt = Wfc_t; N = 512;  ti = wb - 192; }
  const int ntn = N >> 6;
  const int kt = ti / ntn, nt = ti % ntn;
  const int k0 = kt << 6, n0 = nt << 6;
  {
    const int r = tid >> 4, c4 = tid & 15;
#pragma unroll
    for (int e = 0; e < 4; ++e) {
      int row = r + e * 16;
      f32x4 v = *reinterpret_cast<const f32x4*>(&W[(size_t)(k0 + row) * N + n0 + c4 * 4]);
      tile[row][c4 * 4 + 0] = v[0]; tile[row][c4 * 4 + 1] = v[1];
      tile[row][c4 * 4 + 2] = v[2]; tile[row][c4 * 4 + 3] = v[3];
    }
  }
  __syncthreads();
  {
    const int n = tid >> 2, qd = tid & 3;
#pragma unroll
    for (int e = 0; e < 2; ++e) {
      int c = qd * 2 + e;
      u16x8 o;
#pragma unroll
      for (int j = 0; j < 8; ++j) o[j] = f2bf(tile[c * 8 + j][n]);
      *reinterpret_cast<u16x8*>(&Wt[(size_t)(n0 + n) * 512 + k0 + c * 8]) = o;
    }
  }
}

// ---------------- 256x256 NT GEMM body (round-15 schedule, known-best) ----------
// TRIPLE-buffered A + double-buffered B in LDS (160KB), staged 2 K-tiles ahead,
// end-of-tile vmcnt(8); A-fragment ds_reads register-double-buffered with
// counted lgkmcnt(4); 2 barriers/K-tile.
template <bool OUT_F32>
__device__ __forceinline__ void gemm_body(const u16* __restrict__ A,
                                          const u16* __restrict__ Bt,
                                          void* __restrict__ Cp, int N, int K,
                                          int bid0, int nwg,
                                          u16 (*Al)[16384], u16 (*Bl)[16384]) {
  const int nbn = N >> 8;
  const int cpx = nwg >> 3;
  const int bid = (bid0 & 7) * cpx + (bid0 >> 3);
  const int bm = bid / nbn, bn = bid % nbn;
  const size_t row0 = (size_t)bm << 8, col0 = (size_t)bn << 8;
  const int tid = threadIdx.x, lane = tid & 63;
  const int wv = tid >> 6, wm = wv >> 2, wn = wv & 3;
  const int ro = lane & 15, g4 = lane >> 4;
  const int NT = K >> 6;

  const int ci0 = tid, ci1 = tid + 512;
  const int r0 = ci0 >> 3, g0 = (ci0 & 7) ^ (r0 & 7);
  const int r1 = ci1 >> 3, g1 = (ci1 & 7) ^ (r1 & 7);

  auto stageA = [&](int half, int kt, u16* L) {
    gl_lds16(A + (row0 + half * 128 + r0) * (size_t)K + kt * 64 + g0 * 8, L + half * 8192 + ci0 * 8);
    gl_lds16(A + (row0 + half * 128 + r1) * (size_t)K + kt * 64 + g1 * 8, L + half * 8192 + ci1 * 8);
  };
  auto stageB = [&](int half, int kt, u16* L) {
    gl_lds16(Bt + (col0 + half * 128 + r0) * (size_t)K + kt * 64 + g0 * 8, L + half * 8192 + ci0 * 8);
    gl_lds16(Bt + (col0 + half * 128 + r1) * (size_t)K + kt * 64 + g1 * 8, L + half * 8192 + ci1 * 8);
  };

  const int aB = (wm * 128 + ro) * 64;
  const int bB = (wn * 64 + ro) * 64;
  const int sw0 = (g4 ^ (ro & 7)) * 8;
  const int sw1 = ((g4 + 4) ^ (ro & 7)) * 8;

  auto ldf = [&](const u16* p) { return *reinterpret_cast<const bf16x8*>(p); };

  f32x4 acc[8][4] = {};

  stageA(0, 0, Al[0]); stageA(1, 0, Al[0]);
  stageB(0, 0, Bl[0]); stageB(1, 0, Bl[0]);
  stageA(0, 1, Al[1]); stageA(1, 1, Al[1]);
  stageB(0, 1, Bl[1]); stageB(1, 1, Bl[1]);
  asm volatile("s_waitcnt vmcnt(8)" ::: "memory");
  __builtin_amdgcn_s_barrier();

  u16 *Acur = Al[0], *Anxt = Al[1], *Asta = Al[2];
  u16 *Bcur = Bl[0], *Bnxt = Bl[1];

  for (int u = 0; u < NT; ++u) {
    const bool st = (u + 2) < NT;
    bf16x8 bfr[4][2], afA[2][2], afB[2][2];

    // ---- p0: read all B frags + A(m0,m1); stage A(u+2)h0 into freed buffer ----
#pragma unroll
    for (int n = 0; n < 4; ++n) {
      bfr[n][0] = ldf(Bcur + bB + n * 1024 + sw0);
      bfr[n][1] = ldf(Bcur + bB + n * 1024 + sw1);
    }
    afA[0][0] = ldf(Acur + aB + sw0);        afA[0][1] = ldf(Acur + aB + sw1);
    afA[1][0] = ldf(Acur + aB + 1024 + sw0); afA[1][1] = ldf(Acur + aB + 1024 + sw1);
    if (st) stageA(0, u + 2, Asta);
    asm volatile("s_waitcnt lgkmcnt(0)" ::: "memory");
    __builtin_amdgcn_sched_barrier(0);
    afB[0][0] = ldf(Acur + aB + 2048 + sw0); afB[0][1] = ldf(Acur + aB + 2048 + sw1);
    afB[1][0] = ldf(Acur + aB + 3072 + sw0); afB[1][1] = ldf(Acur + aB + 3072 + sw1);
    __builtin_amdgcn_sched_barrier(0);
    __builtin_amdgcn_s_setprio(1);
#pragma unroll
    for (int m = 0; m < 2; ++m)
#pragma unroll
      for (int n = 0; n < 4; ++n) {
        acc[m][n] = __builtin_amdgcn_mfma_f32_16x16x32_bf16(afA[m][0], bfr[n][0], acc[m][n], 0, 0, 0);
        acc[m][n] = __builtin_amdgcn_mfma_f32_16x16x32_bf16(afA[m][1], bfr[n][1], acc[m][n], 0, 0, 0);
      }
    __builtin_amdgcn_s_setprio(0);
    __builtin_amdgcn_s_barrier();  // all waves' B(+A0) reads of tile u complete

    // ---- p1: stage Ah1(u+2)+Bh0(u+2); issue A(m4,m5); MFMA m2,m3 ----
    if (st) { stageA(1, u + 2, Asta); stageB(0, u + 2, Bcur); }
    afA[0][0] = ldf(Acur + aB + 4096 + sw0); afA[0][1] = ldf(Acur + aB + 4096 + sw1);
    afA[1][0] = ldf(Acur + aB + 5120 + sw0); afA[1][1] = ldf(Acur + aB + 5120 + sw1);
    asm volatile("s_waitcnt lgkmcnt(4)" ::: "memory");
    __builtin_amdgcn_sched_barrier(0);
    __builtin_amdgcn_s_setprio(1);
#pragma unroll
    for (int m = 0; m < 2; ++m)
#pragma unroll
      for (int n = 0; n < 4; ++n) {
        acc[2 + m][n] = __builtin_amdgcn_mfma_f32_16x16x32_bf16(afB[m][0], bfr[n][0], acc[2 + m][n], 0, 0, 0);
        acc[2 + m][n] = __builtin_amdgcn_mfma_f32_16x16x32_bf16(afB[m][1], bfr[n][1], acc[2 + m][n], 0, 0, 0);
      }
    __builtin_amdgcn_s_setprio(0);

    // ---- p2: stage Bh1(u+2); issue A(m6,m7); MFMA m4,m5 ----
    if (st) stageB(1, u + 2, Bcur);
    afB[0][0] = ldf(Acur + aB + 6144 + sw0); afB[0][1] = ldf(Acur + aB + 6144 + sw1);
    afB[1][0] = ldf(Acur + aB + 7168 + sw0); afB[1][1] = ldf(Acur + aB + 7168 + sw1);
    asm volatile("s_waitcnt lgkmcnt(4)" ::: "memory");
    __builtin_amdgcn_sched_barrier(0);
    __builtin_amdgcn_s_setprio(1);
#pragma unroll
    for (int m = 0; m < 2; ++m)
#pragma unroll
      for (int n = 0; n < 4; ++n) {
        acc[4 + m][n] = __builtin_amdgcn_mfma_f32_16x16x32_bf16(afA[m][0], bfr[n][0], acc[4 + m][n], 0, 0, 0);
        acc[4 + m][n] = __builtin_amdgcn_mfma_f32_16x16x32_bf16(afA[m][1], bfr[n][1], acc[4 + m][n], 0, 0, 0);
      }
    __builtin_amdgcn_s_setprio(0);

    // ---- p3: MFMA m6,m7; tile-end drain + publish ----
    asm volatile("s_waitcnt lgkmcnt(0)" ::: "memory");
    __builtin_amdgcn_sched_barrier(0);
    __builtin_amdgcn_s_setprio(1);
#pragma unroll
    for (int m = 0; m < 2; ++m)
#pragma unroll
      for (int n = 0; n < 4; ++n) {
        acc[6 + m][n] = __builtin_amdgcn_mfma_f32_16x16x32_bf16(afB[m][0], bfr[n][0], acc[6 + m][n], 0, 0, 0);
        acc[6 + m][n] = __builtin_amdgcn_mfma_f32_16x16x32_bf16(afB[m][1], bfr[n][1], acc[6 + m][n], 0, 0, 0);
      }
    __builtin_amdgcn_s_setprio(0);
    if (st) asm volatile("s_waitcnt vmcnt(8)" ::: "memory");
    else    asm volatile("s_waitcnt vmcnt(0)" ::: "memory");
    __builtin_amdgcn_s_barrier();

    u16* ta = Acur; Acur = Anxt; Anxt = Asta; Asta = ta;
    u16* tb = Bcur; Bcur = Bnxt; Bnxt = tb;
  }

#pragma unroll
  for (int m = 0; m < 8; ++m)
#pragma unroll
    for (int n = 0; n < 4; ++n)
#pragma unroll
      for (int j = 0; j < 4; ++j) {
        size_t r = row0 + wm * 128 + m * 16 + g4 * 4 + j;
        size_t c = col0 + wn * 64 + n * 16 + ro;
        if (OUT_F32)
          reinterpret_cast<float*>(Cp)[r * N + c] = acc[m][n][j];
        else
          reinterpret_cast<u16*>(Cp)[r * N + c] = f2bf(acc[m][n][j]);
      }
}

// fused q + kv projection GEMMs: blocks 0..511 -> qp (512 wgs), 512..1535 -> kvp.
// Segment bases are multiples of 8 so segment-local XCD swizzle is preserved.
__global__ __launch_bounds__(512, 2) void gemm_qkv(const u16* __restrict__ qa,
                                                   const u16* __restrict__ Wq_t,
                                                   u16* __restrict__ qp,
                                                   const u16* __restrict__ kva,
                                                   const u16* __restrict__ Wkv_t,
                                                   u16* __restrict__ kvp) {
  __shared__ __align__(16) u16 Al[3][16384];
  __shared__ __align__(16) u16 Bl[2][16384];
  if (blockIdx.x < 512)
    gemm_body<false>(qa, Wq_t, qp, 512, 512, blockIdx.x, 512, Al, Bl);
  else
    gemm_body<false>(kva, Wkv_t, kvp, 1024, 512, blockIdx.x - 512, 1024, Al, Bl);
}

__global__ __launch_bounds__(512, 2) void gemm_fc(const u16* __restrict__ A,
                                                  const u16* __restrict__ Wfc_t,
                                                  float* __restrict__ out) {
  __shared__ __align__(16) u16 Al[3][16384];
  __shared__ __align__(16) u16 Bl[2][16384];
  gemm_body<true>(A, Wfc_t, out, 512, 512, blockIdx.x, 512, Al, Bl);
}

// ---------------- window attention (round-16 structure: VALU diet) ----------------
__global__ __launch_bounds__(512, 4) void attn_kernel(const u16* __restrict__ qp,
                                                      const u16* __restrict__ kvp,
                                                      u16* __restrict__ o) {
  __shared__ __align__(16) u16 Kl[256 * 64];
  __shared__ __align__(16) u16 Vt[64 * 256];
  __shared__ __align__(16) u16 Pl[8 * 1024];
  const int bid = blockIdx.x;
  const int h = bid & 7, w = (bid >> 3) & 63, b = bid >> 9;
  const int w1 = w >> 3, w2 = w & 7;
  const int tid = threadIdx.x, lane = tid & 63, wv = tid >> 6;

  auto lrow = [&](int t) { return (w1 * 16 + (t >> 4)) * 128 + w2 * 16 + (t & 15); };

#pragma unroll
  for (int p = 0; p < 4; ++p) {
    int ci = tid + p * 512;
    int r = ci >> 3, g = (ci & 7) ^ (r & 7);
    gl_lds16(kvp + ((size_t)(b * LL + lrow(r))) * 1024 + h * 64 + g * 8, Kl + ci * 8);
  }
  // stage V transposed, swizzled; pairwise b32 writes (2 tokens x 16 d / thread)
  {
    const int pr = tid >> 2;
    const int dg = tid & 3;
    const int t0 = 2 * pr;
    const size_t b0 = ((size_t)(b * LL + lrow(t0))) * 1024 + 512 + h * 64 + dg * 16;
    const size_t b1 = ((size_t)(b * LL + lrow(t0 + 1))) * 1024 + 512 + h * 64 + dg * 16;
    u16x8 v00 = *reinterpret_cast<const u16x8*>(kvp + b0);
    u16x8 v01 = *reinterpret_cast<const u16x8*>(kvp + b0 + 8);
    u16x8 v10 = *reinterpret_cast<const u16x8*>(kvp + b1);
    u16x8 v11 = *reinterpret_cast<const u16x8*>(kvp + b1 + 8);
#pragma unroll
    for (int e = 0; e < 8; ++e) {
      int d = dg * 16 + e;
      *reinterpret_cast<u16x2*>(
          &Vt[d * 256 + (((t0 >> 3) ^ (d & 7)) * 8) + (t0 & 7)]) = (u16x2){v00[e], v10[e]};
    }
#pragma unroll
    for (int e = 0; e < 8; ++e) {
      int d = dg * 16 + 8 + e;
      *reinterpret_cast<u16x2*>(
          &Vt[d * 256 + (((t0 >> 3) ^ (d & 7)) * 8) + (t0 & 7)]) = (u16x2){v01[e], v11[e]};
    }
  }
  __syncthreads();

  const int ro = lane & 15;
  const int g4 = lane >> 4;
  const float kk = 0.125f * 1.44269504f;  // scale * log2(e)
  const int swA = (g4 ^ (ro & 7)) * 8;
  const int swB = ((g4 + 4) ^ (ro & 7)) * 8;
  u16* PW = Pl + wv * 1024;

  auto ldf = [&](const u16* p) { return *reinterpret_cast<const bf16x8*>(p); };

#pragma unroll
  for (int rt = 0; rt < 2; ++rt) {
    const int tq = 32 * wv + 16 * rt + ro;
    const size_t qbase = ((size_t)(b * LL + lrow(tq))) * 512 + h * 64 + g4 * 8;
    const bf16x8 qf0 = *reinterpret_cast<const bf16x8*>(qp + qbase);
    const bf16x8 qf1 = *reinterpret_cast<const bf16x8*>(qp + qbase + 32);

    f32x4 sa[16] = {};
    __builtin_amdgcn_s_setprio(1);
#pragma unroll
    for (int ct = 0; ct < 16; ++ct) {
      bf16x8 kf0 = ldf(Kl + (16 * ct + ro) * 64 + swA);
      bf16x8 kf1 = ldf(Kl + (16 * ct + ro) * 64 + swB);
      sa[ct] = __builtin_amdgcn_mfma_f32_16x16x32_bf16(qf0, kf0, sa[ct], 0, 0, 0);
      sa[ct] = __builtin_amdgcn_mfma_f32_16x16x32_bf16(qf1, kf1, sa[ct], 0, 0, 0);
    }
    __builtin_amdgcn_s_setprio(0);

    // softmax per q-row: unnormalized P (defer 1/s to O-write), exp2 folded scale
    float inv4[4];
#pragma unroll
    for (int j = 0; j < 4; ++j) {
      float t8[8];
#pragma unroll
      for (int i = 0; i < 8; ++i) t8[i] = fmaxf(sa[i][j], sa[i + 8][j]);
      float t4a = fmaxf(t8[0], t8[1]), t4b = fmaxf(t8[2], t8[3]);
      float t4c = fmaxf(t8[4], t8[5]), t4d = fmaxf(t8[6], t8[7]);
      float m = fmaxf(fmaxf(t4a, t4b), fmaxf(t4c, t4d));
      m = fmaxf(m, __shfl_xor(m, 1));
      m = fmaxf(m, __shfl_xor(m, 2));
      m = fmaxf(m, __shfl_xor(m, 4));
      m = fmaxf(m, __shfl_xor(m, 8));
      const float mk = m * kk;
      float s = 0.f;
#pragma unroll
      for (int ct = 0; ct < 16; ++ct) {
        float p = exp2f(sa[ct][j] * kk - mk);
        sa[ct][j] = p;
        s += p;
      }
      s += __shfl_xor(s, 1);
      s += __shfl_xor(s, 2);
      s += __shfl_xor(s, 4);
      s += __shfl_xor(s, 8);
      inv4[j] = 1.f / s;
    }

    f32x4 oacc[4] = {};
#pragma unroll
    for (int kh = 0; kh < 4; ++kh) {
#pragma unroll
      for (int c = 0; c < 4; ++c)
#pragma unroll
        for (int j = 0; j < 4; ++j) {
          int rq = g4 * 4 + j;
          PW[rq * 64 + (((2 * c + (ro >> 3)) ^ (rq & 7)) * 8) + (ro & 7)] =
              f2bf(sa[kh * 4 + c][j]);
        }
      __builtin_amdgcn_s_setprio(1);
#pragma unroll
      for (int ks = 0; ks < 2; ++ks) {
        bf16x8 pf = ldf(PW + ro * 64 + (((ks * 4 + g4) ^ (ro & 7)) * 8));
        const int kkg = kh * 2 + ks;
#pragma unroll
        for (int cd = 0; cd < 4; ++cd) {
          bf16x8 vf = ldf(Vt + (16 * cd + ro) * 256 + (((kkg * 4 + g4) ^ (ro & 7)) * 8));
          oacc[cd] = __builtin_amdgcn_mfma_f32_16x16x32_bf16(pf, vf, oacc[cd], 0, 0, 0);
        }
      }
      __builtin_amdgcn_s_setprio(0);
    }

#pragma unroll
    for (int cd = 0; cd < 4; ++cd)
#pragma unroll
      for (int j = 0; j < 4; ++j) {
        int t = 32 * wv + 16 * rt + g4 * 4 + j;
        int d = 16 * cd + ro;
        o[((size_t)(b * LL + lrow(t))) * 512 + h * 64 + d] = f2bf(oacc[cd][j] * inv4[j]);
      }
  }
}

// ---------------- launch ----------------
extern "C" void kernel_launch(void* const* d_in, const int* in_sizes, int n_in,
                              void* d_out, int out_size, void* d_ws, size_t ws_size,
                              hipStream_t stream) {
  const float* q = (const float*)d_in[0];
  const float* kv = (const float*)d_in[1];
  const float* Wq = (const float*)d_in[2];
  const float* Wkv = (const float*)d_in[3];
  const float* Wfc = (const float*)d_in[4];
  float* out = (float*)d_out;
  char* ws = (char*)d_ws;

  u16* q_bf  = (u16*)(ws + 0);            // 67108864  (also reused as o_buf)
  u16* kv_bf = (u16*)(ws + 67108864);     // 67108864
  u16* qp    = (u16*)(ws + 134217728);    // 67108864
  u16* kvp   = (u16*)(ws + 201326592);    // 134217728
  u16* Wq_t  = (u16*)(ws + 335544320);    // 524288
  u16* Wkv_t = (u16*)(ws + 336068608);    // 1048576
  u16* Wfc_t = (u16*)(ws + 337117184);    // 524288
  u16* o_buf = q_bf;

  prep_kernel<<<4352, 256, 0, stream>>>(q, kv, Wq, Wkv, Wfc, q_bf, kv_bf, Wq_t, Wkv_t, Wfc_t);

  gemm_qkv<<<1536, 512, 0, stream>>>(q_bf, Wq_t, qp, kv_bf, Wkv_t, kvp);

  attn_kernel<<<BB * 64 * 8, 512, 0, stream>>>(qp, kvp, o_buf);

  gemm_fc<<<512, 512, 0, stream>>>(o_buf, Wfc_t, out);
}